// Round 15
// baseline (3200.298 us; speedup 1.0000x reference)
//
#include <hip/hip_runtime.h>
#include <math.h>

#define BB 4
#define NN 6000
#define BN (BB*NN)      // 24000
#define SS 48
#define PQ (SS*SS)      // 2304
#define TT 550
#define HH 128

#define TPQ 96          // pq tile = 2 p-rows x 48 q  (outer-product aligned)
#define TTILE 64        // t tile
#define NTILES 9        // ceil(550/64)
#define KT 16           // k chunk
#define SPLITK 8
#define CAP 6144        // slots per tile (expected max ~3900, 1.6x headroom)
#define MLP_E 64        // electrons per block in prep

__device__ __constant__ float kINV_2PI = 1.0f / (2.0f * 3.14159f);
__device__ __constant__ float kGAUSS_NORM = 0.3989422804f;
#define LOG2E 1.4426950408889634f

__device__ __forceinline__ float fexp2(float x) { return __builtin_amdgcn_exp2f(x); }

// ------- Kernel 1: MLP + binning + binned spatial gaussians (merged) -------
__global__ __launch_bounds__(256) void prep_kernel(
    const float* __restrict__ si, const float* __restrict__ zpos,
    const float* __restrict__ mask,
    const float* __restrict__ W1, const float* __restrict__ b1,
    const float* __restrict__ W2, const float* __restrict__ b2,
    const float* __restrict__ W3, const float* __restrict__ b3,
    const float* __restrict__ sensor, const float* __restrict__ el_spread,
    const float* __restrict__ nn_bin_sigma,
    int* __restrict__ counts,
    float* __restrict__ GxT, float* __restrict__ GyT, float* __restrict__ zT)
{
  __shared__ float sh1T[HH][MLP_E];       // 32 KB, [i][e]
  __shared__ float sW1[2 * HH];
  __shared__ float sb1[HH], sb2[HH], sW3[HH];
  __shared__ float sex[MLP_E], sey[MLP_E], sresp[MLP_E], slin[SS];
  __shared__ int   sSlot[NTILES][MLP_E];  // slot of electron e in tile j, or -1
  int tid = threadIdx.x;
  if (tid < 2 * HH) sW1[tid] = W1[tid];
  if (tid < HH) { sb1[tid] = b1[tid]; sb2[tid] = b2[tid]; sW3[tid] = W3[tid]; }
  if (tid < SS) slin[tid] = sensor[tid * SS * 2];  // lin[p]
  int e0 = blockIdx.x * MLP_E;
  int e = tid & 63;
  float x0 = si[2 * (e0 + e)], x1 = si[2 * (e0 + e) + 1];
  if (tid < MLP_E) { sex[tid] = x0; sey[tid] = x1; }
  __syncthreads();
  int jb = (tid >> 6) * 32;
  #pragma unroll
  for (int jj = 0; jj < 32; ++jj) {
    int j = jb + jj;
    sh1T[j][e] = fmaxf(x0 * sW1[j] + x1 * sW1[HH + j] + sb1[j], 0.0f);
  }
  __syncthreads();
  int c4 = (tid & 31) * 4;
  int eh = tid >> 5;  // 0..7
  float acc[8][4] = {};
  for (int i = 0; i < HH; ++i) {
    float4 w  = *(const float4*)&W2[i * HH + c4];
    float4 ha = *(const float4*)&sh1T[i][eh * 8];
    float4 hb = *(const float4*)&sh1T[i][eh * 8 + 4];
    float hv[8] = {ha.x, ha.y, ha.z, ha.w, hb.x, hb.y, hb.z, hb.w};
    #pragma unroll
    for (int ee = 0; ee < 8; ++ee) {
      acc[ee][0] += hv[ee] * w.x; acc[ee][1] += hv[ee] * w.y;
      acc[ee][2] += hv[ee] * w.z; acc[ee][3] += hv[ee] * w.w;
    }
  }
  float outp[8];
  #pragma unroll
  for (int ee = 0; ee < 8; ++ee) {
    float sacc = 0.0f;
    #pragma unroll
    for (int cc = 0; cc < 4; ++cc)
      sacc += fmaxf(acc[ee][cc] + sb2[c4 + cc], 0.0f) * sW3[c4 + cc];
    outp[ee] = sacc;
  }
  #pragma unroll
  for (int off = 1; off < 32; off <<= 1)
    #pragma unroll
    for (int ee = 0; ee < 8; ++ee)
      outp[ee] += __shfl_xor(outp[ee], off);
  if ((tid & 31) == 0) {
    float b3v = b3[0];
    #pragma unroll
    for (int ee = 0; ee < 8; ++ee) {
      int eidx = e0 + eh * 8 + ee;
      sresp[eh * 8 + ee] = fexp2((outp[ee] + b3v) * LOG2E) * mask[eidx];
    }
  }
  __syncthreads();
  // ---- binning: wave 0 only, <=9 atomics/block ----
  if (tid < 64) {
    float sbv = nn_bin_sigma[0];
    float bs = sbv * sbv;
    float Wz = ceilf(sqrtf(128.0f * bs));  // drop terms suppressed by <= e^-64
    float z = zpos[e0 + tid];
    int jlo = (int)floorf((z - Wz) * (1.0f / TTILE));
    int jhi = (int)floorf((z + Wz) * (1.0f / TTILE));
    jlo = jlo < 0 ? 0 : jlo;
    jhi = jhi > NTILES - 1 ? NTILES - 1 : jhi;
    int lane = tid;
    for (int j = 0; j < NTILES; ++j) {
      bool c = (j >= jlo) && (j <= jhi);
      unsigned long long m = __ballot(c);
      int s = -1;
      if (m != 0ull) {
        int leader = __ffsll(m) - 1;
        int base = 0;
        if (lane == leader) base = atomicAdd(&counts[j], __popcll(m));
        base = __shfl(base, leader);
        if (c) {
          int slot = base + __popcll(m & ((1ull << lane) - 1ull));
          if (slot < CAP) { s = slot; zT[j * CAP + slot] = z; }
        }
      }
      sSlot[j][lane] = s;
    }
  }
  __syncthreads();
  float es = el_spread[0];
  float var = es * es;
  float c = (0.5f / var) * LOG2E;
  float sbv = nn_bin_sigma[0];
  float bs = sbv * sbv;
  float amul = (kINV_2PI / var) * (kGAUSS_NORM / sqrtf(bs));
  for (int v = tid; v < MLP_E * SS; v += 256) {
    int ei = v / SS;
    int p = v - ei * SS;
    float lp = slin[p];
    float dx = sex[ei] - lp, dy = sey[ei] - lp;
    float gx = fexp2(-dx * dx * c) * sresp[ei] * amul;
    float gy = fexp2(-dy * dy * c);
    #pragma unroll
    for (int j = 0; j < NTILES; ++j) {
      int s = sSlot[j][ei];
      if (s >= 0) {
        GxT[(j * CAP + s) * SS + p] = gx;
        GyT[(j * CAP + s) * SS + p] = gy;
      }
    }
  }
}

// ------- Kernel 2: contraction, 96x64 tile, LDS double-buffer prefetch -------
// Staging regs per thread: ~11 floats (1.5x gy float4 + 1.5x gx + z) so the
// async-split (issue loads -> compute -> product+store) stays under VGPR 64
// (R10's failure mode was 70+ staging regs -> occupancy cliff).
__global__ __launch_bounds__(256, 8) void gemm_kernel(
    const float* __restrict__ GxT, const float* __restrict__ GyT,
    const float* __restrict__ zT, const int* __restrict__ counts,
    const float* __restrict__ nn_bin_sigma, float* __restrict__ part)
{
  __shared__ __attribute__((aligned(16))) float Asm[2][KT][TPQ];   // 12 KB
  __shared__ __attribute__((aligned(16))) float Esm[2][KT][TTILE]; // 8 KB

  int tid = threadIdx.x;
  int pqBase = blockIdx.x * TPQ;
  int pBase = pqBase / SS;    // base p row (2 per block)
  int tileT = blockIdx.y;
  int tBase = tileT * TTILE;
  int bz = blockIdx.z;

  float s = nn_bin_sigma[0];
  float c2 = (0.5f * LOG2E) / (s * s);

  int count = counts[tileT];
  if (count > CAP) count = CAP;
  int chunks = (count + KT - 1) / KT;
  int cpsBase = chunks / SPLITK;
  int rem = chunks - cpsBase * SPLITK;
  int myC = cpsBase + (bz < rem ? 1 : 0);
  int chunk0 = bz * cpsBase + (bz < rem ? bz : rem);
  int k0 = chunk0 * KT;
  int kend = k0 + myC * KT;   // may exceed count; guarded via mask/clamp

  const float* __restrict__ Gxb = GxT + tileT * CAP * SS;
  const float* __restrict__ Gyb = GyT + tileT * CAP * SS;
  const float* __restrict__ zb  = zT + tileT * CAP;

  // A staging decomposition: 16 rows x 24 float4-chunks = 384 chunks.
  int r0 = tid / 24,          c0 = (tid - r0 * 24) * 4;
  int t2 = tid + 256;
  int r1 = t2 / 24,           c1 = (t2 - r1 * 24) * 4;
  int pl0 = (c0 >= SS) ? 1 : 0, ql0 = c0 - pl0 * SS;
  int pl1 = (c1 >= SS) ? 1 : 0, ql1 = c1 - pl1 * SS;

  int eR = tid >> 4;          // E staging row
  int eC = (tid & 15) * 4;    // E staging col
  int tpq = (tid >> 4) * 6;   // compute pq base (6 per thread)
  int tt  = (tid & 15) * 4;   // compute t base

  // staging registers (LOAD fills; STORE computes products/exp2 and flushes)
  float4 gyA, gyB;
  float  gxA, gxB, mA, mB, zv;

  // count >= 1 guaranteed whenever LOADC executes (myC >= 1 -> chunks >= 1)
  #define LOADC(KC)                                                        \
    {                                                                      \
      int kA = (KC) + r0;                                                  \
      int kAc = kA < count ? kA : count - 1;                               \
      mA = (kA < count) ? 1.0f : 0.0f;                                     \
      gyA = *(const float4*)&Gyb[kAc * SS + ql0];                          \
      gxA = Gxb[kAc * SS + pBase + pl0];                                   \
      if (tid < 128) {                                                     \
        int kB = (KC) + r1;                                                \
        int kBc = kB < count ? kB : count - 1;                             \
        mB = (kB < count) ? 1.0f : 0.0f;                                   \
        gyB = *(const float4*)&Gyb[kBc * SS + ql1];                        \
        gxB = Gxb[kBc * SS + pBase + pl1];                                 \
      }                                                                    \
      int ek = (KC) + eR;                                                  \
      int ekc = ek < count ? ek : count - 1;                               \
      float zl = zb[ekc];                                                  \
      zv = (ek < count) ? zl : -1.0e6f; /* exp2 underflows to exactly 0 */ \
    }

  #define STOREC(BUF)                                                      \
    {                                                                      \
      float gA = gxA * mA;                                                 \
      *(float4*)&Asm[BUF][r0][c0] =                                        \
          make_float4(gA * gyA.x, gA * gyA.y, gA * gyA.z, gA * gyA.w);     \
      if (tid < 128) {                                                     \
        float gB = gxB * mB;                                               \
        *(float4*)&Asm[BUF][r1][c1] =                                      \
            make_float4(gB * gyB.x, gB * gyB.y, gB * gyB.z, gB * gyB.w);   \
      }                                                                    \
      float d0 = (float)(tBase + eC)     - zv;                             \
      float d1 = (float)(tBase + eC + 1) - zv;                             \
      float d2 = (float)(tBase + eC + 2) - zv;                             \
      float d3 = (float)(tBase + eC + 3) - zv;                             \
      *(float4*)&Esm[BUF][eR][eC] =                                        \
          make_float4(fexp2(-d0 * d0 * c2), fexp2(-d1 * d1 * c2),          \
                      fexp2(-d2 * d2 * c2), fexp2(-d3 * d3 * c2));         \
    }

  float acc[6][4] = {};

  if (k0 < kend) { LOADC(k0); STOREC(0); }
  __syncthreads();
  int cur = 0;

  for (int kc = k0; kc < kend; kc += KT) {
    bool more = (kc + KT < kend);
    if (more) LOADC(kc + KT);           // issue next chunk's loads early
    #pragma unroll
    for (int k2 = 0; k2 < KT; ++k2) {   // compute current chunk from LDS
      float4 a0 = *(const float4*)&Asm[cur][k2][tpq];
      float2 a1 = *(const float2*)&Asm[cur][k2][tpq + 4];
      float4 e4 = *(const float4*)&Esm[cur][k2][tt];
      float aa[6] = {a0.x, a0.y, a0.z, a0.w, a1.x, a1.y};
      float ee[4] = {e4.x, e4.y, e4.z, e4.w};
      #pragma unroll
      for (int i2 = 0; i2 < 6; ++i2)
        #pragma unroll
        for (int j2 = 0; j2 < 4; ++j2)
          acc[i2][j2] += aa[i2] * ee[j2];
    }
    if (more) { STOREC(cur ^ 1); cur ^= 1; }
    __syncthreads();
  }

  // plain coalesced partial store (zeros when myC==0)
  float* pb = part + ((tileT * SPLITK + bz) * PQ) * TTILE;
  #pragma unroll
  for (int i = 0; i < 6; ++i) {
    int pq = pqBase + tpq + i;
    *(float4*)&pb[pq * TTILE + tt] =
        make_float4(acc[i][0], acc[i][1], acc[i][2], acc[i][3]);
  }
}

// ---------------- Kernel 3: reduce partials -> out ----------------
__global__ __launch_bounds__(256) void reduce_kernel(
    const float* __restrict__ part, float* __restrict__ out)
{
  int i = blockIdx.x * 256 + threadIdx.x;
  if (i >= PQ * TT) return;
  int pq = i / TT;
  int t = i - pq * TT;
  int tileT = t >> 6;
  int tl = t & 63;
  const float* p = part + ((tileT * SPLITK) * PQ + pq) * TTILE + tl;
  float sum = 0.0f;
  #pragma unroll
  for (int s2 = 0; s2 < SPLITK; ++s2)
    sum += p[s2 * (PQ * TTILE)];
  out[i] = sum;
}

extern "C" void kernel_launch(void* const* d_in, const int* in_sizes, int n_in,
                              void* d_out, int out_size, void* d_ws, size_t ws_size,
                              hipStream_t stream) {
  const float* si     = (const float*)d_in[0];
  const float* zpos   = (const float*)d_in[1];
  const float* mask   = (const float*)d_in[2];
  const float* sensor = (const float*)d_in[3];
  const float* W1     = (const float*)d_in[4];
  const float* b1     = (const float*)d_in[5];
  const float* W2     = (const float*)d_in[6];
  const float* b2     = (const float*)d_in[7];
  const float* W3     = (const float*)d_in[8];
  const float* b3     = (const float*)d_in[9];
  const float* el_spread    = (const float*)d_in[10];
  const float* nn_bin_sigma = (const float*)d_in[11];
  float* out = (float*)d_out;

  float* ws    = (float*)d_ws;
  float* part  = ws;                              // 9*8*2304*64 = 10.6M floats
  float* GxT   = part + NTILES * SPLITK * PQ * TTILE;
  float* GyT   = GxT + NTILES * CAP * SS;         // 9*6144*48
  float* zT    = GyT + NTILES * CAP * SS;         // 9*6144
  int*   counts = (int*)(zT + NTILES * CAP);      // 16

  hipMemsetAsync(counts, 0, 16 * sizeof(int), stream);
  prep_kernel<<<BN / MLP_E, 256, 0, stream>>>(si, zpos, mask, W1, b1, W2, b2, W3, b3,
                                              sensor, el_spread, nn_bin_sigma,
                                              counts, GxT, GyT, zT);
  gemm_kernel<<<dim3(PQ / TPQ, NTILES, SPLITK), 256, 0, stream>>>(
      GxT, GyT, zT, counts, nn_bin_sigma, part);
  reduce_kernel<<<(PQ * TT + 255) / 256, 256, 0, stream>>>(part, out);
}